// Round 3
// baseline (215.948 us; speedup 1.0000x reference)
//
#include <hip/hip_runtime.h>
#include <math.h>

// Problem constants
#define BB 2
#define SS 2048
#define DD 256
#define NTOK (BB * SS)          // 4096
#define N_QK 8192
#define N_V  8192
#define NCPS 32
#define MPC  16
#define NC   144                // 9 * MPC candidates per side
#define K_QK 32
#define K_V  64
#define OUT_GATES (3 * NTOK * NC)   // offset of pos_loss scalar

__device__ __forceinline__ float blockSum(float v, volatile float* red) {
    for (int o = 32; o; o >>= 1) v += __shfl_down(v, o, 64);
    int lane = threadIdx.x & 63, wid = threadIdx.x >> 6;
    __syncthreads();
    if (lane == 0) red[wid] = v;
    __syncthreads();
    return red[0] + red[1] + red[2] + red[3];
}

__device__ __forceinline__ float blockMin(float v, volatile float* red) {
    for (int o = 32; o; o >>= 1) v = fminf(v, __shfl_down(v, o, 64));
    int lane = threadIdx.x & 63, wid = threadIdx.x >> 6;
    __syncthreads();
    if (lane == 0) red[wid] = v;
    __syncthreads();
    return fminf(fminf(red[0], red[1]), fminf(red[2], red[3]));
}

__device__ __forceinline__ float blockMax(float v, volatile float* red) {
    for (int o = 32; o; o >>= 1) v = fmaxf(v, __shfl_down(v, o, 64));
    int lane = threadIdx.x & 63, wid = threadIdx.x >> 6;
    __syncthreads();
    if (lane == 0) red[wid] = v;
    __syncthreads();
    return fmaxf(fmaxf(red[0], red[1]), fmaxf(red[2], red[3]));
}

__global__ __launch_bounds__(256) void router_main(
    const float* __restrict__ x,
    const float* __restrict__ qk_neurons,
    const float* __restrict__ v_neurons,
    const float* __restrict__ neuron_pos,
    const float* __restrict__ W_pos_qk, const float* __restrict__ b_pos_qk,
    const float* __restrict__ W_pos_v,  const float* __restrict__ b_pos_v,
    const float* __restrict__ W_tau,    const float* __restrict__ b_tau,
    const int* __restrict__ cm_qk, const int* __restrict__ cm_v,
    float* __restrict__ out, float* __restrict__ ws)
{
    const int token = blockIdx.x;          // b*S + s
    const int tid   = threadIdx.x;
    const int lane  = tid & 63, wid = tid >> 6;

    __shared__ float  x_s[DD];
    __shared__ float  scal[8];             // [0..1] qk_pos, [2..3] v_pos, [4..6] tau
    __shared__ double partd[4][7];
    __shared__ int    ci_s[2][NC];         // raw cell_map entries (may be -1)
    __shared__ float  sc_s[2][NC];         // scores (with -1e9 fill)
    __shared__ float  d_s[2][NC];          // squared pos distance
    __shared__ float  eg_s[NC];            // per-gate exp_gate
    __shared__ float  red[4];

    // ---- Phase A: load x row, compute 7 small dots in double ----
    float xv = x[(size_t)token * DD + tid];
    x_s[tid] = xv;
    double p[7];
    p[0] = (double)xv * (double)W_pos_qk[tid * 2 + 0];
    p[1] = (double)xv * (double)W_pos_qk[tid * 2 + 1];
    p[2] = (double)xv * (double)W_pos_v[tid * 2 + 0];
    p[3] = (double)xv * (double)W_pos_v[tid * 2 + 1];
    p[4] = (double)xv * (double)W_tau[tid * 3 + 0];
    p[5] = (double)xv * (double)W_tau[tid * 3 + 1];
    p[6] = (double)xv * (double)W_tau[tid * 3 + 2];
    #pragma unroll
    for (int j = 0; j < 7; ++j) {
        double v = p[j];
        for (int o = 32; o; o >>= 1) v += __shfl_down(v, o, 64);
        p[j] = v;
    }
    if (lane == 0) {
        #pragma unroll
        for (int j = 0; j < 7; ++j) partd[wid][j] = p[j];
    }
    __syncthreads();
    if (tid < 7) {
        double v = partd[0][tid] + partd[1][tid] + partd[2][tid] + partd[3][tid];
        float bias = (tid < 2) ? b_pos_qk[tid]
                   : (tid < 4) ? b_pos_v[tid - 2]
                               : b_tau[tid - 4];
        scal[tid] = (float)v + bias;       // f32 dot result + f32 bias (matches ref order)
    }
    __syncthreads();

    // ---- Phase B: candidate lookup + position distances ----
    for (int c = tid; c < 2 * NC; c += 256) {
        int side = (c >= NC);
        int n    = side ? c - NC : c;
        float px = scal[side * 2 + 0], py = scal[side * 2 + 1];
        // normalized = (pos+4)/8 ; cell = trunc(norm*32) clipped
        int cx = (int)(((px + 4.0f) / 8.0f) * 32.0f);
        int cy = (int)(((py + 4.0f) / 8.0f) * 32.0f);
        cx = min(max(cx, 0), NCPS - 1);
        cy = min(max(cy, 0), NCPS - 1);
        int o = n / MPC, slot = n % MPC;
        int nx = min(max(cx + (o / 3 - 1), 0), NCPS - 1);
        int ny = min(max(cy + (o % 3 - 1), 0), NCPS - 1);
        int idx = nx * NCPS + ny;
        int cand = (side ? cm_v : cm_qk)[idx * MPC + slot];
        ci_s[side][n] = cand;
        const float* npos = neuron_pos + (side ? (size_t)N_QK * 2 : 0);
        int cidx = max(cand, 0);
        float dx = px - npos[cidx * 2 + 0];
        float dy = py - npos[cidx * 2 + 1];
        d_s[side][n] = dx * dx + dy * dy;
    }
    __syncthreads();

    // ---- Phase C: 288 dot products, quad-of-lanes per candidate ----
    {
        const int quad = tid >> 2, ql = tid & 3;
        const float4* x4 = (const float4*)x_s;
        for (int c = quad; c < 2 * NC; c += 64) {
            int side = (c >= NC);
            int n    = side ? c - NC : c;
            int cand = ci_s[side][n];
            const float4* row = (const float4*)((side ? v_neurons : qk_neurons)
                                                + (size_t)max(cand, 0) * DD);
            double acc = 0.0;
            #pragma unroll
            for (int i = ql; i < 64; i += 4) {
                float4 r  = row[i];
                float4 xx = x4[i];
                acc += (double)r.x * (double)xx.x + (double)r.y * (double)xx.y
                     + (double)r.z * (double)xx.z + (double)r.w * (double)xx.w;
            }
            acc += __shfl_xor(acc, 1, 64);
            acc += __shfl_xor(acc, 2, 64);
            if (ql == 0)
                sc_s[side][n] = (cand >= 0) ? (float)acc : -1e9f;
        }
    }
    __syncthreads();

    // ---- Phase D: three threshold gates ----
    #pragma unroll 1
    for (int g = 0; g < 3; ++g) {
        const int side = (g == 2);
        const int k    = (g == 2) ? K_V : K_QK;
        const float tau = scal[4 + g];

        if (tid < NC) {
            float s   = sc_s[side][tid];
            float raw = s - tau;
            float gate = (raw > 0.0f) ? raw : 1e-8f * expf(raw);
            eg_s[tid] = expf(gate) - 1.0f;
        }
        __syncthreads();

        float myeg = (tid < NC) ? eg_s[tid] : 0.0f;
        float thr_cand = 3.402823466e38f;
        if (tid < NC) {
            int cnt = 0;
            for (int j = 0; j < NC; ++j) cnt += (eg_s[j] > myeg) ? 1 : 0;
            if (cnt < k) thr_cand = myeg;   // eligible to be the k-th largest
        }
        float thr = blockMin(thr_cand, red);

        float keep = (tid < NC && myeg >= thr) ? myeg : 0.0f;
        float gs   = blockSum(keep, red) + 1e-8f;
        float mx   = blockMax(myeg, red);
        float strength = tanhf(mx);
        float outv = keep / gs * strength;

        if (tid < NC)
            out[((size_t)g * NTOK + token) * NC + tid] = outv;

        if (g == 0 || g == 2) {
            float m = (tid < NC && ci_s[side][tid] >= 0) ? 1.0f : 0.0f;
            float contrib = outv * d_s[side][tid < NC ? tid : 0] * m;
            float wsum = blockSum(contrib, red);
            float csum = blockSum(m, red);
            if (tid == 0) {
                ws[(size_t)token * 4 + (g ? 2 : 0)] = wsum;
                ws[(size_t)token * 4 + (g ? 3 : 1)] = csum;
            }
        }
        __syncthreads();
    }
}

__global__ void router_finalize(const float* __restrict__ ws, float* __restrict__ out) {
    const int t = threadIdx.x;   // 64 threads, single wave
    double wq = 0, cq = 0, wv = 0, cv = 0;
    for (int i = t; i < NTOK; i += 64) {
        wq += (double)ws[(size_t)i * 4 + 0];
        cq += (double)ws[(size_t)i * 4 + 1];
        wv += (double)ws[(size_t)i * 4 + 2];
        cv += (double)ws[(size_t)i * 4 + 3];
    }
    for (int o = 32; o; o >>= 1) {
        wq += __shfl_down(wq, o, 64);
        cq += __shfl_down(cq, o, 64);
        wv += __shfl_down(wv, o, 64);
        cv += __shfl_down(cv, o, 64);
    }
    if (t == 0)
        out[OUT_GATES] = (float)(wq / (cq + 1e-8) + wv / (cv + 1e-8));
}

extern "C" void kernel_launch(void* const* d_in, const int* in_sizes, int n_in,
                              void* d_out, int out_size, void* d_ws, size_t ws_size,
                              hipStream_t stream) {
    const float* x          = (const float*)d_in[0];
    const float* qk_neurons = (const float*)d_in[1];
    const float* v_neurons  = (const float*)d_in[2];
    const float* neuron_pos = (const float*)d_in[3];
    const float* W_pos_qk   = (const float*)d_in[4];
    const float* b_pos_qk   = (const float*)d_in[5];
    const float* W_pos_v    = (const float*)d_in[6];
    const float* b_pos_v    = (const float*)d_in[7];
    const float* W_tau      = (const float*)d_in[8];
    const float* b_tau      = (const float*)d_in[9];
    const int*   cm_qk      = (const int*)d_in[10];
    const int*   cm_v       = (const int*)d_in[11];

    float* out = (float*)d_out;
    float* ws  = (float*)d_ws;

    router_main<<<NTOK, 256, 0, stream>>>(
        x, qk_neurons, v_neurons, neuron_pos,
        W_pos_qk, b_pos_qk, W_pos_v, b_pos_v, W_tau, b_tau,
        cm_qk, cm_v, out, ws);
    router_finalize<<<1, 64, 0, stream>>>(ws, out);
}

// Round 4
// 199.123 us; speedup vs baseline: 1.0845x; 1.0845x over previous
//
#include <hip/hip_runtime.h>
#include <math.h>

// Problem constants
#define BB 2
#define SS 2048
#define DD 256
#define NTOK (BB * SS)          // 4096
#define N_QK 8192
#define N_V  8192
#define NCPS 32
#define MPC  16
#define NC   144                // 9 * MPC candidates per side
#define K_QK 32
#define K_V  64
#define OUT_GATES (3 * NTOK * NC)   // offset of pos_loss scalar

__global__ __launch_bounds__(256) void router_main(
    const float* __restrict__ x,
    const float* __restrict__ qk_neurons,
    const float* __restrict__ v_neurons,
    const float* __restrict__ neuron_pos,
    const float* __restrict__ W_pos_qk, const float* __restrict__ b_pos_qk,
    const float* __restrict__ W_pos_v,  const float* __restrict__ b_pos_v,
    const float* __restrict__ W_tau,    const float* __restrict__ b_tau,
    const int* __restrict__ cm_qk, const int* __restrict__ cm_v,
    float* __restrict__ out, float* __restrict__ ws)
{
    const int token = blockIdx.x;          // b*S + s
    const int tid   = threadIdx.x;
    const int lane  = tid & 63, wid = tid >> 6;

    __shared__ __align__(16) float  x_s[DD];
    __shared__ float  scal[8];             // [0..1] qk_pos, [2..3] v_pos, [4..6] tau
    __shared__ double partd[4][7];
    __shared__ int    ci_s[2][NC];         // raw cell_map entries (may be -1)
    __shared__ float  sc_s[2][NC];         // scores (with -1e9 fill)
    __shared__ float  d_s[2][NC];          // squared pos distance
    __shared__ __align__(16) float eg3[3][NC];   // exp_gate per gate
    __shared__ float  tc3[3][NC];          // per-(gate,j) threshold candidates

    // ---- Phase A: load x row, compute 7 small dots in double ----
    float xv = x[(size_t)token * DD + tid];
    x_s[tid] = xv;
    double p[7];
    p[0] = (double)xv * (double)W_pos_qk[tid * 2 + 0];
    p[1] = (double)xv * (double)W_pos_qk[tid * 2 + 1];
    p[2] = (double)xv * (double)W_pos_v[tid * 2 + 0];
    p[3] = (double)xv * (double)W_pos_v[tid * 2 + 1];
    p[4] = (double)xv * (double)W_tau[tid * 3 + 0];
    p[5] = (double)xv * (double)W_tau[tid * 3 + 1];
    p[6] = (double)xv * (double)W_tau[tid * 3 + 2];
    #pragma unroll
    for (int j = 0; j < 7; ++j) {
        double v = p[j];
        for (int o = 32; o; o >>= 1) v += __shfl_down(v, o, 64);
        p[j] = v;
    }
    if (lane == 0) {
        #pragma unroll
        for (int j = 0; j < 7; ++j) partd[wid][j] = p[j];
    }
    __syncthreads();
    if (tid < 7) {
        double v = partd[0][tid] + partd[1][tid] + partd[2][tid] + partd[3][tid];
        float bias = (tid < 2) ? b_pos_qk[tid]
                   : (tid < 4) ? b_pos_v[tid - 2]
                               : b_tau[tid - 4];
        scal[tid] = (float)v + bias;       // f32 dot result + f32 bias (matches ref order)
    }
    __syncthreads();

    // ---- Phase B: candidate lookup + position distances ----
    for (int c = tid; c < 2 * NC; c += 256) {
        int side = (c >= NC);
        int n    = side ? c - NC : c;
        float px = scal[side * 2 + 0], py = scal[side * 2 + 1];
        int cx = (int)(((px + 4.0f) / 8.0f) * 32.0f);
        int cy = (int)(((py + 4.0f) / 8.0f) * 32.0f);
        cx = min(max(cx, 0), NCPS - 1);
        cy = min(max(cy, 0), NCPS - 1);
        int o = n / MPC, slot = n % MPC;
        int nx = min(max(cx + (o / 3 - 1), 0), NCPS - 1);
        int ny = min(max(cy + (o % 3 - 1), 0), NCPS - 1);
        int idx = nx * NCPS + ny;
        int cand = (side ? cm_v : cm_qk)[idx * MPC + slot];
        ci_s[side][n] = cand;
        const float* npos = neuron_pos + (side ? (size_t)N_QK * 2 : 0);
        int cidx = max(cand, 0);
        float dx = px - npos[cidx * 2 + 0];
        float dy = py - npos[cidx * 2 + 1];
        d_s[side][n] = dx * dx + dy * dy;
    }
    __syncthreads();

    // ---- Phase C: 288 dot products, quad-of-lanes per candidate, 4 f64 acc chains ----
    {
        const int quad = tid >> 2, ql = tid & 3;
        const float4* x4 = (const float4*)x_s;
        for (int c = quad; c < 2 * NC; c += 64) {
            int side = (c >= NC);
            int n    = side ? c - NC : c;
            int cand = ci_s[side][n];
            const float4* row = (const float4*)((side ? v_neurons : qk_neurons)
                                                + (size_t)max(cand, 0) * DD);
            double ax = 0.0, ay = 0.0, az = 0.0, aw = 0.0;
            #pragma unroll
            for (int i = ql; i < 64; i += 4) {
                float4 r  = row[i];
                float4 xx = x4[i];
                ax = fma((double)r.x, (double)xx.x, ax);
                ay = fma((double)r.y, (double)xx.y, ay);
                az = fma((double)r.z, (double)xx.z, az);
                aw = fma((double)r.w, (double)xx.w, aw);
            }
            double acc = (ax + ay) + (az + aw);
            acc += __shfl_xor(acc, 1, 64);
            acc += __shfl_xor(acc, 2, 64);
            if (ql == 0)
                sc_s[side][n] = (cand >= 0) ? (float)acc : -1e9f;
        }
    }
    __syncthreads();

    // ---- Phase D1: exp_gate for all 3 gates in parallel ----
    for (int idx = tid; idx < 3 * NC; idx += 256) {
        int g = (idx >= 2 * NC) ? 2 : (idx >= NC ? 1 : 0);
        int j = idx - g * NC;
        float s   = sc_s[g == 2][j];
        float raw = s - scal[4 + g];
        float gate = (raw > 0.0f) ? raw : 1e-8f * expf(raw);
        eg3[g][j] = expf(gate) - 1.0f;
    }
    __syncthreads();

    // ---- Phase D2: rank counts (float4-vectorized, semantics identical to ref top_k) ----
    for (int idx = tid; idx < 3 * NC; idx += 256) {
        int g = (idx >= 2 * NC) ? 2 : (idx >= NC ? 1 : 0);
        int j = idx - g * NC;
        float my = eg3[g][j];
        const float4* e4 = (const float4*)&eg3[g][0];
        int cnt = 0;
        #pragma unroll
        for (int q = 0; q < NC / 4; ++q) {
            float4 e = e4[q];
            cnt += (e.x > my) + (e.y > my) + (e.z > my) + (e.w > my);
        }
        int k = (g == 2) ? K_V : K_QK;
        tc3[g][j] = (cnt < k) ? my : 3.402823466e38f;
    }
    __syncthreads();

    // ---- Phase D3: one wave per gate — reduce, normalize, write out + loss partials ----
    if (wid < 3) {
        const int g = wid, side = (g == 2);
        const bool has2 = (lane < 16);
        float e0 = eg3[g][lane],       e1 = eg3[g][lane + 64];
        float t0 = tc3[g][lane],       t1 = tc3[g][lane + 64];
        float e2 = has2 ? eg3[g][lane + 128] : 0.0f;
        float t2 = has2 ? tc3[g][lane + 128] : 3.402823466e38f;
        float mn = fminf(fminf(t0, t1), t2);
        float mx = fmaxf(fmaxf(e0, e1), e2);
        #pragma unroll
        for (int o = 32; o; o >>= 1) {
            mn = fminf(mn, __shfl_xor(mn, o, 64));
            mx = fmaxf(mx, __shfl_xor(mx, o, 64));
        }
        const float thr = mn;
        float k0 = (e0 >= thr) ? e0 : 0.0f;
        float k1 = (e1 >= thr) ? e1 : 0.0f;
        float k2 = (has2 && e2 >= thr) ? e2 : 0.0f;
        float sum = k0 + k1 + k2;
        #pragma unroll
        for (int o = 32; o; o >>= 1) sum += __shfl_xor(sum, o, 64);
        const float gs = sum + 1e-8f;
        const float strength = tanhf(mx);
        float o0 = k0 / gs * strength;
        float o1 = k1 / gs * strength;
        float o2 = k2 / gs * strength;
        float* og = out + ((size_t)g * NTOK + token) * NC;
        og[lane]      = o0;
        og[lane + 64] = o1;
        if (has2) og[lane + 128] = o2;

        if (g != 1) {
            float m0 = (ci_s[side][lane]       >= 0) ? 1.0f : 0.0f;
            float m1 = (ci_s[side][lane + 64]  >= 0) ? 1.0f : 0.0f;
            float m2 = (has2 && ci_s[side][lane + 128] >= 0) ? 1.0f : 0.0f;
            float w = o0 * d_s[side][lane] * m0 + o1 * d_s[side][lane + 64] * m1;
            if (has2) w += o2 * d_s[side][lane + 128] * m2;
            float c = m0 + m1 + m2;
            #pragma unroll
            for (int o = 32; o; o >>= 1) {
                w += __shfl_xor(w, o, 64);
                c += __shfl_xor(c, o, 64);
            }
            if (lane == 0) {
                ws[(size_t)token * 4 + (side ? 2 : 0)] = w;
                ws[(size_t)token * 4 + (side ? 3 : 1)] = c;
            }
        }
    }
}

__global__ __launch_bounds__(1024) void router_finalize(
    const float* __restrict__ ws, float* __restrict__ out)
{
    __shared__ double red[16][4];
    const int t = threadIdx.x, lane = t & 63, w = t >> 6;
    double wq = 0, cq = 0, wv = 0, cv = 0;
    const float4* w4 = (const float4*)ws;     // [token] = {wq, cq, wv, cv}
    for (int i = t; i < NTOK; i += 1024) {
        float4 v = w4[i];
        wq += (double)v.x; cq += (double)v.y;
        wv += (double)v.z; cv += (double)v.w;
    }
    for (int o = 32; o; o >>= 1) {
        wq += __shfl_down(wq, o, 64);
        cq += __shfl_down(cq, o, 64);
        wv += __shfl_down(wv, o, 64);
        cv += __shfl_down(cv, o, 64);
    }
    if (lane == 0) { red[w][0] = wq; red[w][1] = cq; red[w][2] = wv; red[w][3] = cv; }
    __syncthreads();
    if (t == 0) {
        double a = 0, b = 0, c = 0, d = 0;
        for (int i = 0; i < 16; ++i) {
            a += red[i][0]; b += red[i][1]; c += red[i][2]; d += red[i][3];
        }
        out[OUT_GATES] = (float)(a / (b + 1e-8) + c / (d + 1e-8));
    }
}

extern "C" void kernel_launch(void* const* d_in, const int* in_sizes, int n_in,
                              void* d_out, int out_size, void* d_ws, size_t ws_size,
                              hipStream_t stream) {
    const float* x          = (const float*)d_in[0];
    const float* qk_neurons = (const float*)d_in[1];
    const float* v_neurons  = (const float*)d_in[2];
    const float* neuron_pos = (const float*)d_in[3];
    const float* W_pos_qk   = (const float*)d_in[4];
    const float* b_pos_qk   = (const float*)d_in[5];
    const float* W_pos_v    = (const float*)d_in[6];
    const float* b_pos_v    = (const float*)d_in[7];
    const float* W_tau      = (const float*)d_in[8];
    const float* b_tau      = (const float*)d_in[9];
    const int*   cm_qk      = (const int*)d_in[10];
    const int*   cm_v       = (const int*)d_in[11];

    float* out = (float*)d_out;
    float* ws  = (float*)d_ws;

    router_main<<<NTOK, 256, 0, stream>>>(
        x, qk_neurons, v_neurons, neuron_pos,
        W_pos_qk, b_pos_qk, W_pos_v, b_pos_v, W_tau, b_tau,
        cm_qk, cm_v, out, ws);
    router_finalize<<<1, 1024, 0, stream>>>(ws, out);
}